// Round 1
// baseline (148.749 us; speedup 1.0000x reference)
//
#include <hip/hip_runtime.h>

#define TM 64
#define F_INC 128
#define K_DIM 256
#define F_OUTC 128
#define CAT_LD 264   // 256 + 8 bf16 pad -> conflict-free ds_read_b128

using fv4   = __attribute__((ext_vector_type(4))) float;
using f32x4 = __attribute__((ext_vector_type(4))) float;
using bf16x8 = __attribute__((ext_vector_type(8))) short;

static __device__ __forceinline__ unsigned short f2bf(float f) {
    union { float f; unsigned u; } v; v.f = f;
    unsigned u = v.u;
    u += 0x7FFFu + ((u >> 16) & 1u);   // round-to-nearest-even
    return (unsigned short)(u >> 16);
}

__global__ __launch_bounds__(256) void sage_fused_kernel(
    const int* __restrict__ row_ptr,
    const int* __restrict__ col_ind,
    const float* __restrict__ x_nbr,   // [N_NBR][128]
    const float* __restrict__ x_tgt,   // [N_TGT][128]
    const float* __restrict__ w,       // [128][256] row-major (o,k)
    const float* __restrict__ lin_b,   // [128]
    const float* __restrict__ bias,    // [128]
    float* __restrict__ out,           // [N_TGT][128]
    int n_tgt)
{
    __shared__ int s_ptr[TM + 1];
    __shared__ int s_idx[TM * 16];
    __shared__ unsigned short s_cat[TM][CAT_LD];

    const int tid = threadIdx.x;
    const int g0  = blockIdx.x * TM;

    // ---- stage row pointers ----
    if (tid < TM + 1) {
        int gp = g0 + tid;
        if (gp > n_tgt) gp = n_tgt;
        s_ptr[tid] = row_ptr[gp];
    }
    __syncthreads();

    // ---- stage edge indices ----
    for (int e = tid; e < TM * 16; e += 256) {
        const int m = e >> 4, j = e & 15;
        const int start = s_ptr[m];
        const int deg = s_ptr[m + 1] - start;
        s_idx[e] = (j < deg) ? col_ind[start + j] : -1;
    }
    __syncthreads();

    // ---- aggregation: 32 lanes per target row, float4 per lane ----
    {
        const int lane32 = tid & 31;
        const int grp = tid >> 5;       // 8 groups of 32 lanes
        for (int m = grp; m < TM; m += 8) {
            const int gm = g0 + m;
            // target half of cat
            fv4 t = {0.f, 0.f, 0.f, 0.f};
            if (gm < n_tgt)
                t = *(const fv4*)(x_tgt + (size_t)gm * F_INC + lane32 * 4);
            {
                ushort4 p;
                p.x = f2bf(t[0]); p.y = f2bf(t[1]); p.z = f2bf(t[2]); p.w = f2bf(t[3]);
                *(ushort4*)&s_cat[m][lane32 * 4] = p;
            }
            // mean-aggregate half
            const int deg = s_ptr[m + 1] - s_ptr[m];
            fv4 acc = {0.f, 0.f, 0.f, 0.f};
            const int* idx = &s_idx[m * 16];
            if (deg == 16) {
#pragma unroll
                for (int j = 0; j < 16; ++j) {
                    const int c = idx[j];
                    acc += *(const fv4*)(x_nbr + (size_t)c * F_INC + lane32 * 4);
                }
            } else {
                for (int j = 0; j < deg; ++j) {
                    const int c = idx[j];
                    acc += *(const fv4*)(x_nbr + (size_t)c * F_INC + lane32 * 4);
                }
            }
            const float sc = 1.0f / (float)(deg > 0 ? deg : 1);
            acc *= sc;
            {
                ushort4 p;
                p.x = f2bf(acc[0]); p.y = f2bf(acc[1]); p.z = f2bf(acc[2]); p.w = f2bf(acc[3]);
                *(ushort4*)&s_cat[m][128 + lane32 * 4] = p;
            }
        }
    }
    __syncthreads();

    // ---- GEMM: cat[64][256](bf16) @ W^T -> out tile [64][128] ----
    const int lane = tid & 63;
    const int wave = tid >> 6;      // 4 waves
    const int col  = lane & 15;     // A-row / B-col / D-col within 16x16 tile
    const int kq   = lane >> 4;     // 0..3 -> k-subblock of 8
    const int r0   = kq * 4;        // D row base for this lane

    // B fragments: wave owns o-tiles {wave*16, 64+wave*16}, full K in regs
    bf16x8 bfr[2][8];
#pragma unroll
    for (int h = 0; h < 2; ++h) {
        const int o = h * 64 + wave * 16 + col;
        const float* wrow = w + (size_t)o * K_DIM;
#pragma unroll
        for (int kt = 0; kt < 8; ++kt) {
            const float* p = wrow + kt * 32 + kq * 8;
            fv4 lo = *(const fv4*)p;
            fv4 hi = *(const fv4*)(p + 4);
            bf16x8 b;
            b[0] = (short)f2bf(lo[0]); b[1] = (short)f2bf(lo[1]);
            b[2] = (short)f2bf(lo[2]); b[3] = (short)f2bf(lo[3]);
            b[4] = (short)f2bf(hi[0]); b[5] = (short)f2bf(hi[1]);
            b[6] = (short)f2bf(hi[2]); b[7] = (short)f2bf(hi[3]);
            bfr[h][kt] = b;
        }
    }

    const int o0 = wave * 16 + col;
    const int o1 = 64 + o0;
    const float bs0 = lin_b[o0] + bias[o0];
    const float bs1 = lin_b[o1] + bias[o1];

#pragma unroll 1
    for (int mt = 0; mt < 4; ++mt) {
        const int mrow = mt * 16 + col;   // A fragment row for this lane
        bf16x8 afr[8];
#pragma unroll
        for (int kt = 0; kt < 8; ++kt)
            afr[kt] = *(const bf16x8*)&s_cat[mrow][kt * 32 + kq * 8];

        f32x4 acc0 = {0.f, 0.f, 0.f, 0.f};
        f32x4 acc1 = {0.f, 0.f, 0.f, 0.f};
#pragma unroll
        for (int kt = 0; kt < 8; ++kt) {
            acc0 = __builtin_amdgcn_mfma_f32_16x16x32_bf16(afr[kt], bfr[0][kt], acc0, 0, 0, 0);
            acc1 = __builtin_amdgcn_mfma_f32_16x16x32_bf16(afr[kt], bfr[1][kt], acc1, 0, 0, 0);
        }

#pragma unroll
        for (int i = 0; i < 4; ++i) {
            const int gm = g0 + mt * 16 + r0 + i;
            if (gm < n_tgt) {
                out[(size_t)gm * F_OUTC + o0] = acc0[i] + bs0;
                out[(size_t)gm * F_OUTC + o1] = acc1[i] + bs1;
            }
        }
    }
}

extern "C" void kernel_launch(void* const* d_in, const int* in_sizes, int n_in,
                              void* d_out, int out_size, void* d_ws, size_t ws_size,
                              hipStream_t stream) {
    const int*   row_ptr = (const int*)d_in[0];
    const int*   col_ind = (const int*)d_in[1];
    // d_in[2] = sample_count (unused by reference math)
    const float* x_nbr   = (const float*)d_in[3];
    const float* x_tgt   = (const float*)d_in[4];
    const float* w       = (const float*)d_in[5];
    const float* lb      = (const float*)d_in[6];
    const float* bs      = (const float*)d_in[7];
    float* out = (float*)d_out;

    const int n_tgt = in_sizes[0] - 1;
    const int grid = (n_tgt + TM - 1) / TM;
    hipLaunchKernelGGL(sage_fused_kernel, dim3(grid), dim3(256), 0, stream,
                       row_ptr, col_ind, x_nbr, x_tgt, w, lb, bs, out, n_tgt);
}

// Round 2
// 105.925 us; speedup vs baseline: 1.4043x; 1.4043x over previous
//
#include <hip/hip_runtime.h>

#define TM 64
#define F_INC 128
#define K_DIM 256
#define F_OUTC 128
#define CAT_LD 264   // 256 + 8 bf16 pad

using fv4    = __attribute__((ext_vector_type(4))) float;
using f32x4  = __attribute__((ext_vector_type(4))) float;
using bf16x8 = __attribute__((ext_vector_type(8))) short;
using u16x8  = __attribute__((ext_vector_type(8))) unsigned short;

static __device__ __forceinline__ unsigned short f2bf(float f) {
    union { float f; unsigned u; } v; v.f = f;
    unsigned u = v.u;
    u += 0x7FFFu + ((u >> 16) & 1u);   // RNE
    return (unsigned short)(u >> 16);
}
static __device__ __forceinline__ float bf2f(unsigned short h) {
    union { unsigned u; float f; } v; v.u = ((unsigned)h) << 16;
    return v.f;
}

// ---- streaming fp32 -> bf16 conversion, 8 elems/thread ----
__global__ __launch_bounds__(256) void f32_to_bf16_kernel(
    const float* __restrict__ src, unsigned short* __restrict__ dst, int n8)
{
    const int i = blockIdx.x * 256 + threadIdx.x;
    if (i < n8) {
        const fv4 a = *(const fv4*)(src + (size_t)i * 8);
        const fv4 b = *(const fv4*)(src + (size_t)i * 8 + 4);
        u16x8 o;
        o[0] = f2bf(a[0]); o[1] = f2bf(a[1]); o[2] = f2bf(a[2]); o[3] = f2bf(a[3]);
        o[4] = f2bf(b[0]); o[5] = f2bf(b[1]); o[6] = f2bf(b[2]); o[7] = f2bf(b[3]);
        *(u16x8*)(dst + (size_t)i * 8) = o;
    }
}

// ---- fused gather+mean+concat+GEMM ----
// USE_WS=1: x_nbr / w read as bf16 from d_ws tables. USE_WS=0: fp32 fallback.
template <int USE_WS>
__global__ __launch_bounds__(256) void sage_fused_kernel(
    const int* __restrict__ row_ptr,
    const int* __restrict__ col_ind,
    const float* __restrict__ x_nbr,              // [N_NBR][128] fp32
    const unsigned short* __restrict__ nbr_bf,    // [N_NBR][128] bf16 (ws)
    const float* __restrict__ x_tgt,              // [N_TGT][128]
    const float* __restrict__ w,                  // [128][256] fp32
    const unsigned short* __restrict__ w_bf,      // [128][256] bf16 (ws)
    const float* __restrict__ lin_b,
    const float* __restrict__ bias,
    float* __restrict__ out,                      // [N_TGT][128]
    int n_tgt)
{
    __shared__ int s_ptr[TM + 1];
    __shared__ int s_idx[TM * 16];
    __shared__ unsigned short s_cat[TM][CAT_LD];

    const int tid = threadIdx.x;
    const int g0  = blockIdx.x * TM;

    if (tid < TM + 1) {
        int gp = g0 + tid;
        if (gp > n_tgt) gp = n_tgt;
        s_ptr[tid] = row_ptr[gp];
    }
    __syncthreads();

    for (int e = tid; e < TM * 16; e += 256) {
        const int m = e >> 4, j = e & 15;
        const int start = s_ptr[m];
        const int deg = s_ptr[m + 1] - start;
        s_idx[e] = (j < deg) ? col_ind[start + j] : 0;
    }
    __syncthreads();

    if (USE_WS) {
        // 16 lanes per row, 8 bf16 (16B) per lane
        const int team = tid >> 4;      // 0..15
        const int lt   = tid & 15;
        for (int m = team; m < TM; m += 16) {
            const int gm = g0 + m;
            // target half
            u16x8 t = {0, 0, 0, 0, 0, 0, 0, 0};
            if (gm < n_tgt) {
                const fv4 a = *(const fv4*)(x_tgt + (size_t)gm * F_INC + lt * 8);
                const fv4 b = *(const fv4*)(x_tgt + (size_t)gm * F_INC + lt * 8 + 4);
                t[0] = f2bf(a[0]); t[1] = f2bf(a[1]); t[2] = f2bf(a[2]); t[3] = f2bf(a[3]);
                t[4] = f2bf(b[0]); t[5] = f2bf(b[1]); t[6] = f2bf(b[2]); t[7] = f2bf(b[3]);
            }
            *(u16x8*)&s_cat[m][lt * 8] = t;
            // mean aggregate (bf16 table)
            const int deg = s_ptr[m + 1] - s_ptr[m];
            float acc[8] = {0, 0, 0, 0, 0, 0, 0, 0};
            const int* idx = &s_idx[m * 16];
            if (deg == 16) {
#pragma unroll
                for (int j = 0; j < 16; ++j) {
                    const u16x8 v = *(const u16x8*)(nbr_bf + (size_t)idx[j] * F_INC + lt * 8);
#pragma unroll
                    for (int i = 0; i < 8; ++i) acc[i] += bf2f(v[i]);
                }
            } else {
                for (int j = 0; j < deg; ++j) {
                    const u16x8 v = *(const u16x8*)(nbr_bf + (size_t)idx[j] * F_INC + lt * 8);
#pragma unroll
                    for (int i = 0; i < 8; ++i) acc[i] += bf2f(v[i]);
                }
            }
            const float sc = 1.0f / (float)(deg > 0 ? deg : 1);
            u16x8 p;
#pragma unroll
            for (int i = 0; i < 8; ++i) p[i] = f2bf(acc[i] * sc);
            *(u16x8*)&s_cat[m][128 + lt * 8] = p;
        }
    } else {
        // fp32 fallback: 32 lanes per row, float4 per lane
        const int lane32 = tid & 31;
        const int grp = tid >> 5;
        for (int m = grp; m < TM; m += 8) {
            const int gm = g0 + m;
            fv4 t = {0.f, 0.f, 0.f, 0.f};
            if (gm < n_tgt)
                t = *(const fv4*)(x_tgt + (size_t)gm * F_INC + lane32 * 4);
            {
                ushort4 p;
                p.x = f2bf(t[0]); p.y = f2bf(t[1]); p.z = f2bf(t[2]); p.w = f2bf(t[3]);
                *(ushort4*)&s_cat[m][lane32 * 4] = p;
            }
            const int deg = s_ptr[m + 1] - s_ptr[m];
            fv4 acc = {0.f, 0.f, 0.f, 0.f};
            const int* idx = &s_idx[m * 16];
            if (deg == 16) {
#pragma unroll
                for (int j = 0; j < 16; ++j)
                    acc += *(const fv4*)(x_nbr + (size_t)idx[j] * F_INC + lane32 * 4);
            } else {
                for (int j = 0; j < deg; ++j)
                    acc += *(const fv4*)(x_nbr + (size_t)idx[j] * F_INC + lane32 * 4);
            }
            const float sc = 1.0f / (float)(deg > 0 ? deg : 1);
            acc *= sc;
            {
                ushort4 p;
                p.x = f2bf(acc[0]); p.y = f2bf(acc[1]); p.z = f2bf(acc[2]); p.w = f2bf(acc[3]);
                *(ushort4*)&s_cat[m][128 + lane32 * 4] = p;
            }
        }
    }
    __syncthreads();

    // ---- GEMM: s_cat[64][256](bf16) @ W^T -> out tile [64][128] ----
    const int lane = tid & 63;
    const int wave = tid >> 6;
    const int col  = lane & 15;
    const int kq   = lane >> 4;
    const int r0   = kq * 4;

    bf16x8 bfr[2][8];
#pragma unroll
    for (int h = 0; h < 2; ++h) {
        const int o = h * 64 + wave * 16 + col;
#pragma unroll
        for (int kt = 0; kt < 8; ++kt) {
            if (USE_WS) {
                bfr[h][kt] = *(const bf16x8*)(w_bf + (size_t)o * K_DIM + kt * 32 + kq * 8);
            } else {
                const float* p = w + (size_t)o * K_DIM + kt * 32 + kq * 8;
                fv4 lo = *(const fv4*)p;
                fv4 hi = *(const fv4*)(p + 4);
                bf16x8 b;
                b[0] = (short)f2bf(lo[0]); b[1] = (short)f2bf(lo[1]);
                b[2] = (short)f2bf(lo[2]); b[3] = (short)f2bf(lo[3]);
                b[4] = (short)f2bf(hi[0]); b[5] = (short)f2bf(hi[1]);
                b[6] = (short)f2bf(hi[2]); b[7] = (short)f2bf(hi[3]);
                bfr[h][kt] = b;
            }
        }
    }

    const int o0 = wave * 16 + col;
    const int o1 = 64 + o0;
    const float bs0 = lin_b[o0] + bias[o0];
    const float bs1 = lin_b[o1] + bias[o1];

#pragma unroll 1
    for (int mt = 0; mt < 4; ++mt) {
        const int mrow = mt * 16 + col;
        bf16x8 afr[8];
#pragma unroll
        for (int kt = 0; kt < 8; ++kt)
            afr[kt] = *(const bf16x8*)&s_cat[mrow][kt * 32 + kq * 8];

        f32x4 acc0 = {0.f, 0.f, 0.f, 0.f};
        f32x4 acc1 = {0.f, 0.f, 0.f, 0.f};
#pragma unroll
        for (int kt = 0; kt < 8; ++kt) {
            acc0 = __builtin_amdgcn_mfma_f32_16x16x32_bf16(afr[kt], bfr[0][kt], acc0, 0, 0, 0);
            acc1 = __builtin_amdgcn_mfma_f32_16x16x32_bf16(afr[kt], bfr[1][kt], acc1, 0, 0, 0);
        }

#pragma unroll
        for (int i = 0; i < 4; ++i) {
            const int gm = g0 + mt * 16 + r0 + i;
            if (gm < n_tgt) {
                out[(size_t)gm * F_OUTC + o0] = acc0[i] + bs0;
                out[(size_t)gm * F_OUTC + o1] = acc1[i] + bs1;
            }
        }
    }
}

extern "C" void kernel_launch(void* const* d_in, const int* in_sizes, int n_in,
                              void* d_out, int out_size, void* d_ws, size_t ws_size,
                              hipStream_t stream) {
    const int*   row_ptr = (const int*)d_in[0];
    const int*   col_ind = (const int*)d_in[1];
    const float* x_nbr   = (const float*)d_in[3];
    const float* x_tgt   = (const float*)d_in[4];
    const float* w       = (const float*)d_in[5];
    const float* lb      = (const float*)d_in[6];
    const float* bs      = (const float*)d_in[7];
    float* out = (float*)d_out;

    const int n_tgt  = in_sizes[0] - 1;
    const int n_nbrf = in_sizes[3];        // N_NBR * 128
    const int n_wf   = in_sizes[5];        // 128 * 256
    const int grid   = (n_tgt + TM - 1) / TM;

    const size_t nbr_bytes = (size_t)n_nbrf * 2;
    const size_t need = nbr_bytes + (size_t)n_wf * 2;

    if (ws_size >= need) {
        unsigned short* nbr_bf = (unsigned short*)d_ws;
        unsigned short* w_bf   = (unsigned short*)((char*)d_ws + nbr_bytes);
        const int n8n = n_nbrf / 8;
        const int n8w = n_wf / 8;
        hipLaunchKernelGGL(f32_to_bf16_kernel, dim3((n8n + 255) / 256), dim3(256), 0, stream,
                           x_nbr, nbr_bf, n8n);
        hipLaunchKernelGGL(f32_to_bf16_kernel, dim3((n8w + 255) / 256), dim3(256), 0, stream,
                           w, w_bf, n8w);
        hipLaunchKernelGGL(sage_fused_kernel<1>, dim3(grid), dim3(256), 0, stream,
                           row_ptr, col_ind, x_nbr, nbr_bf, x_tgt, w, w_bf, lb, bs, out, n_tgt);
    } else {
        hipLaunchKernelGGL(sage_fused_kernel<0>, dim3(grid), dim3(256), 0, stream,
                           row_ptr, col_ind, x_nbr, (const unsigned short*)nullptr,
                           x_tgt, w, (const unsigned short*)nullptr, lb, bs, out, n_tgt);
    }
}

// Round 3
// 84.332 us; speedup vs baseline: 1.7639x; 1.2561x over previous
//
#include <hip/hip_runtime.h>

#define TM 64
#define F_INC 128
#define K_DIM 256
#define F_OUTC 128
#define CAT_LD 264   // 256 + 8 bf16 pad

using fv2    = __attribute__((ext_vector_type(2))) float;
using fv4    = __attribute__((ext_vector_type(4))) float;
using f32x4  = __attribute__((ext_vector_type(4))) float;
using bf16x8 = __attribute__((ext_vector_type(8))) short;
using u16x8  = __attribute__((ext_vector_type(8))) unsigned short;

static __device__ __forceinline__ unsigned short f2bf(float f) {
    union { float f; unsigned u; } v; v.f = f;
    unsigned u = v.u;
    u += 0x7FFFu + ((u >> 16) & 1u);   // RNE
    return (unsigned short)(u >> 16);
}

// ---- streaming fp32 -> bf16 (for W) ----
__global__ __launch_bounds__(256) void f32_to_bf16_kernel(
    const float* __restrict__ src, unsigned short* __restrict__ dst, int n8)
{
    const int i = blockIdx.x * 256 + threadIdx.x;
    if (i < n8) {
        const fv4 a = *(const fv4*)(src + (size_t)i * 8);
        const fv4 b = *(const fv4*)(src + (size_t)i * 8 + 4);
        u16x8 o;
        o[0] = f2bf(a[0]); o[1] = f2bf(a[1]); o[2] = f2bf(a[2]); o[3] = f2bf(a[3]);
        o[4] = f2bf(b[0]); o[5] = f2bf(b[1]); o[6] = f2bf(b[2]); o[7] = f2bf(b[3]);
        *(u16x8*)(dst + (size_t)i * 8) = o;
    }
}

// ---- streaming fp32 -> fp8(e4m3, HW cvt) for the neighbor table ----
__global__ __launch_bounds__(256) void f32_to_fp8_kernel(
    const float* __restrict__ src, unsigned int* __restrict__ dst, int n8)
{
    const int i = blockIdx.x * 256 + threadIdx.x;
    if (i < n8) {
        const fv4 a = *(const fv4*)(src + (size_t)i * 8);
        const fv4 b = *(const fv4*)(src + (size_t)i * 8 + 4);
        unsigned int w0 = (unsigned)__builtin_amdgcn_cvt_pk_fp8_f32(a[0], a[1], 0, false);
        w0 = (unsigned)__builtin_amdgcn_cvt_pk_fp8_f32(a[2], a[3], (int)w0, true);
        unsigned int w1 = (unsigned)__builtin_amdgcn_cvt_pk_fp8_f32(b[0], b[1], 0, false);
        w1 = (unsigned)__builtin_amdgcn_cvt_pk_fp8_f32(b[2], b[3], (int)w1, true);
        uint2 o; o.x = w0; o.y = w1;
        *(uint2*)(dst + (size_t)i * 2) = o;
    }
}

// ---- fused gather+mean+concat+GEMM ----
// USE_WS=1: neighbor table fp8 in ws, W bf16 in ws. USE_WS=0: fp32 fallback.
template <int USE_WS>
__global__ __launch_bounds__(256) void sage_fused_kernel(
    const int* __restrict__ row_ptr,
    const int* __restrict__ col_ind,
    const float* __restrict__ x_nbr,              // [N_NBR][128] fp32
    const unsigned int* __restrict__ nbr_f8,      // [N_NBR][32] u32 (128 fp8) ws
    const float* __restrict__ x_tgt,              // [N_TGT][128]
    const float* __restrict__ w,                  // [128][256] fp32
    const unsigned short* __restrict__ w_bf,      // [128][256] bf16 ws
    const float* __restrict__ lin_b,
    const float* __restrict__ bias,
    float* __restrict__ out,                      // [N_TGT][128]
    int n_tgt)
{
    __shared__ int s_ptr[TM + 1];
    __shared__ int s_idx[TM * 16];
    __shared__ unsigned short s_cat[TM][CAT_LD];

    const int tid = threadIdx.x;
    const int g0  = blockIdx.x * TM;

    if (tid < TM + 1) {
        int gp = g0 + tid;
        if (gp > n_tgt) gp = n_tgt;
        s_ptr[tid] = row_ptr[gp];
    }
    __syncthreads();

    for (int e = tid; e < TM * 16; e += 256) {
        const int m = e >> 4, j = e & 15;
        const int start = s_ptr[m];
        const int deg = s_ptr[m + 1] - start;
        s_idx[e] = (j < deg) ? col_ind[start + j] : 0;
    }
    __syncthreads();

    if (USE_WS) {
        // 8 lanes per row; each lane owns 16 features (16 fp8 bytes = 1 uint4)
        const int team = tid >> 3;      // 0..31
        const int lt   = tid & 7;       // lane-in-team
        for (int mi = 0; mi < 2; ++mi) {
            const int m  = team + mi * 32;
            const int gm = g0 + m;
            // ---- target half of cat: 16 floats/lane ----
            {
                u16x8 t0 = {0,0,0,0,0,0,0,0}, t1 = {0,0,0,0,0,0,0,0};
                if (gm < n_tgt) {
                    const float* tp = x_tgt + (size_t)gm * F_INC + lt * 16;
                    const fv4 a = *(const fv4*)(tp);
                    const fv4 b = *(const fv4*)(tp + 4);
                    const fv4 c = *(const fv4*)(tp + 8);
                    const fv4 d = *(const fv4*)(tp + 12);
                    t0[0]=f2bf(a[0]); t0[1]=f2bf(a[1]); t0[2]=f2bf(a[2]); t0[3]=f2bf(a[3]);
                    t0[4]=f2bf(b[0]); t0[5]=f2bf(b[1]); t0[6]=f2bf(b[2]); t0[7]=f2bf(b[3]);
                    t1[0]=f2bf(c[0]); t1[1]=f2bf(c[1]); t1[2]=f2bf(c[2]); t1[3]=f2bf(c[3]);
                    t1[4]=f2bf(d[0]); t1[5]=f2bf(d[1]); t1[6]=f2bf(d[2]); t1[7]=f2bf(d[3]);
                }
                *(u16x8*)&s_cat[m][lt * 16]     = t0;
                *(u16x8*)&s_cat[m][lt * 16 + 8] = t1;
            }
            // ---- mean aggregate from fp8 table ----
            const int deg = s_ptr[m + 1] - s_ptr[m];
            float acc[16];
#pragma unroll
            for (int i = 0; i < 16; ++i) acc[i] = 0.f;
            const int* idx = &s_idx[m * 16];
            if (deg == 16) {
#pragma unroll
                for (int j = 0; j < 16; ++j) {
                    const uint4 v = *(const uint4*)(nbr_f8 + (size_t)idx[j] * 32 + lt * 4);
                    fv2 p;
                    p = __builtin_amdgcn_cvt_pk_f32_fp8(v.x, false); acc[0]+=p[0];  acc[1]+=p[1];
                    p = __builtin_amdgcn_cvt_pk_f32_fp8(v.x, true ); acc[2]+=p[0];  acc[3]+=p[1];
                    p = __builtin_amdgcn_cvt_pk_f32_fp8(v.y, false); acc[4]+=p[0];  acc[5]+=p[1];
                    p = __builtin_amdgcn_cvt_pk_f32_fp8(v.y, true ); acc[6]+=p[0];  acc[7]+=p[1];
                    p = __builtin_amdgcn_cvt_pk_f32_fp8(v.z, false); acc[8]+=p[0];  acc[9]+=p[1];
                    p = __builtin_amdgcn_cvt_pk_f32_fp8(v.z, true ); acc[10]+=p[0]; acc[11]+=p[1];
                    p = __builtin_amdgcn_cvt_pk_f32_fp8(v.w, false); acc[12]+=p[0]; acc[13]+=p[1];
                    p = __builtin_amdgcn_cvt_pk_f32_fp8(v.w, true ); acc[14]+=p[0]; acc[15]+=p[1];
                }
            } else {
                for (int j = 0; j < deg; ++j) {
                    const uint4 v = *(const uint4*)(nbr_f8 + (size_t)idx[j] * 32 + lt * 4);
                    fv2 p;
                    p = __builtin_amdgcn_cvt_pk_f32_fp8(v.x, false); acc[0]+=p[0];  acc[1]+=p[1];
                    p = __builtin_amdgcn_cvt_pk_f32_fp8(v.x, true ); acc[2]+=p[0];  acc[3]+=p[1];
                    p = __builtin_amdgcn_cvt_pk_f32_fp8(v.y, false); acc[4]+=p[0];  acc[5]+=p[1];
                    p = __builtin_amdgcn_cvt_pk_f32_fp8(v.y, true ); acc[6]+=p[0];  acc[7]+=p[1];
                    p = __builtin_amdgcn_cvt_pk_f32_fp8(v.z, false); acc[8]+=p[0];  acc[9]+=p[1];
                    p = __builtin_amdgcn_cvt_pk_f32_fp8(v.z, true ); acc[10]+=p[0]; acc[11]+=p[1];
                    p = __builtin_amdgcn_cvt_pk_f32_fp8(v.w, false); acc[12]+=p[0]; acc[13]+=p[1];
                    p = __builtin_amdgcn_cvt_pk_f32_fp8(v.w, true ); acc[14]+=p[0]; acc[15]+=p[1];
                }
            }
            const float sc = 1.0f / (float)(deg > 0 ? deg : 1);
            u16x8 p0, p1;
#pragma unroll
            for (int i = 0; i < 8; ++i) { p0[i] = f2bf(acc[i] * sc); p1[i] = f2bf(acc[8 + i] * sc); }
            *(u16x8*)&s_cat[m][128 + lt * 16]     = p0;
            *(u16x8*)&s_cat[m][128 + lt * 16 + 8] = p1;
        }
    } else {
        // fp32 fallback: 32 lanes per row, float4 per lane
        const int lane32 = tid & 31;
        const int grp = tid >> 5;
        for (int m = grp; m < TM; m += 8) {
            const int gm = g0 + m;
            fv4 t = {0.f, 0.f, 0.f, 0.f};
            if (gm < n_tgt)
                t = *(const fv4*)(x_tgt + (size_t)gm * F_INC + lane32 * 4);
            {
                ushort4 p;
                p.x = f2bf(t[0]); p.y = f2bf(t[1]); p.z = f2bf(t[2]); p.w = f2bf(t[3]);
                *(ushort4*)&s_cat[m][lane32 * 4] = p;
            }
            const int deg = s_ptr[m + 1] - s_ptr[m];
            fv4 acc = {0.f, 0.f, 0.f, 0.f};
            const int* idx = &s_idx[m * 16];
            if (deg == 16) {
#pragma unroll
                for (int j = 0; j < 16; ++j)
                    acc += *(const fv4*)(x_nbr + (size_t)idx[j] * F_INC + lane32 * 4);
            } else {
                for (int j = 0; j < deg; ++j)
                    acc += *(const fv4*)(x_nbr + (size_t)idx[j] * F_INC + lane32 * 4);
            }
            const float sc = 1.0f / (float)(deg > 0 ? deg : 1);
            acc *= sc;
            {
                ushort4 p;
                p.x = f2bf(acc[0]); p.y = f2bf(acc[1]); p.z = f2bf(acc[2]); p.w = f2bf(acc[3]);
                *(ushort4*)&s_cat[m][128 + lane32 * 4] = p;
            }
        }
    }
    __syncthreads();

    // ---- GEMM: s_cat[64][256](bf16) @ W^T -> out tile [64][128] ----
    const int lane = tid & 63;
    const int wave = tid >> 6;
    const int col  = lane & 15;
    const int kq   = lane >> 4;
    const int r0   = kq * 4;

    bf16x8 bfr[2][8];
#pragma unroll
    for (int h = 0; h < 2; ++h) {
        const int o = h * 64 + wave * 16 + col;
#pragma unroll
        for (int kt = 0; kt < 8; ++kt) {
            if (USE_WS) {
                bfr[h][kt] = *(const bf16x8*)(w_bf + (size_t)o * K_DIM + kt * 32 + kq * 8);
            } else {
                const float* p = w + (size_t)o * K_DIM + kt * 32 + kq * 8;
                fv4 lo = *(const fv4*)p;
                fv4 hi = *(const fv4*)(p + 4);
                bf16x8 b;
                b[0] = (short)f2bf(lo[0]); b[1] = (short)f2bf(lo[1]);
                b[2] = (short)f2bf(lo[2]); b[3] = (short)f2bf(lo[3]);
                b[4] = (short)f2bf(hi[0]); b[5] = (short)f2bf(hi[1]);
                b[6] = (short)f2bf(hi[2]); b[7] = (short)f2bf(hi[3]);
                bfr[h][kt] = b;
            }
        }
    }

    const int o0 = wave * 16 + col;
    const int o1 = 64 + o0;
    const float bs0 = lin_b[o0] + bias[o0];
    const float bs1 = lin_b[o1] + bias[o1];

#pragma unroll 1
    for (int mt = 0; mt < 4; ++mt) {
        const int mrow = mt * 16 + col;
        bf16x8 afr[8];
#pragma unroll
        for (int kt = 0; kt < 8; ++kt)
            afr[kt] = *(const bf16x8*)&s_cat[mrow][kt * 32 + kq * 8];

        f32x4 acc0 = {0.f, 0.f, 0.f, 0.f};
        f32x4 acc1 = {0.f, 0.f, 0.f, 0.f};
#pragma unroll
        for (int kt = 0; kt < 8; ++kt) {
            acc0 = __builtin_amdgcn_mfma_f32_16x16x32_bf16(afr[kt], bfr[0][kt], acc0, 0, 0, 0);
            acc1 = __builtin_amdgcn_mfma_f32_16x16x32_bf16(afr[kt], bfr[1][kt], acc1, 0, 0, 0);
        }

#pragma unroll
        for (int i = 0; i < 4; ++i) {
            const int gm = g0 + mt * 16 + r0 + i;
            if (gm < n_tgt) {
                out[(size_t)gm * F_OUTC + o0] = acc0[i] + bs0;
                out[(size_t)gm * F_OUTC + o1] = acc1[i] + bs1;
            }
        }
    }
}

extern "C" void kernel_launch(void* const* d_in, const int* in_sizes, int n_in,
                              void* d_out, int out_size, void* d_ws, size_t ws_size,
                              hipStream_t stream) {
    const int*   row_ptr = (const int*)d_in[0];
    const int*   col_ind = (const int*)d_in[1];
    const float* x_nbr   = (const float*)d_in[3];
    const float* x_tgt   = (const float*)d_in[4];
    const float* w       = (const float*)d_in[5];
    const float* lb      = (const float*)d_in[6];
    const float* bs      = (const float*)d_in[7];
    float* out = (float*)d_out;

    const int n_tgt  = in_sizes[0] - 1;
    const int n_nbrf = in_sizes[3];        // N_NBR * 128
    const int n_wf   = in_sizes[5];        // 128 * 256
    const int grid   = (n_tgt + TM - 1) / TM;

    const size_t nbr_bytes = (size_t)n_nbrf;          // 1 B per element (fp8)
    const size_t need = nbr_bytes + (size_t)n_wf * 2;

    if (ws_size >= need) {
        unsigned int*   nbr_f8 = (unsigned int*)d_ws;
        unsigned short* w_bf   = (unsigned short*)((char*)d_ws + nbr_bytes);
        const int n8n = n_nbrf / 8;
        const int n8w = n_wf / 8;
        hipLaunchKernelGGL(f32_to_fp8_kernel, dim3((n8n + 255) / 256), dim3(256), 0, stream,
                           x_nbr, nbr_f8, n8n);
        hipLaunchKernelGGL(f32_to_bf16_kernel, dim3((n8w + 255) / 256), dim3(256), 0, stream,
                           w, w_bf, n8w);
        hipLaunchKernelGGL(sage_fused_kernel<1>, dim3(grid), dim3(256), 0, stream,
                           row_ptr, col_ind, x_nbr, nbr_f8, x_tgt, w, w_bf, lb, bs, out, n_tgt);
    } else {
        hipLaunchKernelGGL(sage_fused_kernel<0>, dim3(grid), dim3(256), 0, stream,
                           row_ptr, col_ind, x_nbr, (const unsigned int*)nullptr,
                           x_tgt, w, (const unsigned short*)nullptr, lb, bs, out, n_tgt);
    }
}